// Round 8
// baseline (311.055 us; speedup 1.0000x reference)
//
#include <hip/hip_runtime.h>
#include <math.h>

// Problem constants: B=2, S=2048, E=1024, NH=16, hd=64, T=1 (seq = S)
#define BB 2
#define SS 2048
#define EE 1024
#define NHH 16
#define HD 64
#define HD2 32

typedef _Float16 f16x8 __attribute__((ext_vector_type(8)));   // 8 f16 = 4 VGPRs
typedef __attribute__((ext_vector_type(4))) float f32x4;      // MFMA accumulator

// pack two fp32 -> half2 with RNE (v_cvt_f16_f32 x2 + pack). RNE is essential:
// RTZ's one-sided bias accumulates over K=1024 dots (would give ~1e-2 error).
static __device__ __forceinline__ unsigned pkh(float a, float b) {
    union { _Float16 h[2]; unsigned u; } v;
    v.h[0] = (_Float16)a; v.h[1] = (_Float16)b;
    return v.u;
}

// ---- async global->LDS DMA, 16B per lane (global_load_lds_dwordx4) ----
static __device__ __forceinline__ void dma16(const void* g, void* l) {
    __builtin_amdgcn_global_load_lds(
        (const __attribute__((address_space(1))) unsigned int*)g,
        (__attribute__((address_space(3))) unsigned int*)l,
        16, 0, 0);
}

// ---------------- kernel 1: RoPE cos/sin tables ----------------
__global__ __launch_bounds__(256) void rope_table_k(float* __restrict__ ct,
                                                    float* __restrict__ st) {
    int idx = blockIdx.x * 256 + threadIdx.x;   // idx = s*32 + p
    if (idx >= SS * HD2) return;
    int s = idx >> 5, p = idx & 31;
    double inv = pow(10000.0, -(double)(2 * p) / 64.0);
    double ang = (double)s * inv;
    ct[idx] = (float)cos(ang);
    st[idx] = (float)sin(ang);
}

// ---------------- kernel 2: QKV GEMM (f16 RNE, single-product MFMA) -------
// C = X @ W^T + bias. 128x128 tile, BK=64 (16 iters), 4 waves each 64x64.
// Q pre-scaled by 0.125*log2(e). Outputs f16 in MFMA-fragment swizzles:
//   Q/K per bh (131072 f16): e = (((s>>4)*2 + (d>>5))*4 + ((d>>3)&3))*128 + (s&15)*8 + (d&7)
//   V  per bh:               e = (((s>>5)*4 + (d>>4))*4 + ((s>>3)&3))*128 + (d&15)*8 + (s&7)
__global__ __launch_bounds__(256, 3) void qkv_mfma_k(
    const float* __restrict__ X, const float* __restrict__ W,
    const float* __restrict__ bias,
    const float* __restrict__ ct, const float* __restrict__ st,
    unsigned short* __restrict__ Qg, unsigned short* __restrict__ Kg,
    unsigned short* __restrict__ Vg)
{
    __shared__ __align__(16) unsigned short Alds[8192];   // 128 rows x 64 k, f16: 16 KB
    __shared__ __align__(16) unsigned short Blds[8192];

    const int tid  = threadIdx.x;
    const int wave = tid >> 6;
    const int lane = tid & 63;
    const int quad = lane >> 4;
    const int l15  = lane & 15;
    const int m0   = blockIdx.y * 128;
    const int n0b  = blockIdx.x * 128;

    // staging: row r (0..127), k-chunk half*32
    const int r    = tid >> 1;
    const int half = tid & 1;
    const int grp_s = r >> 4;
    const int l15s  = r & 15;

    const float* ap = X + (size_t)(m0 + r) * EE + half * 32;
    const float* bp = W + (size_t)(n0b + r) * EE + half * 32;

    f32x4 acc[4][4];
#pragma unroll
    for (int mc = 0; mc < 4; mc++)
#pragma unroll
        for (int nc = 0; nc < 4; nc++) acc[mc][nc] = (f32x4){0.f, 0.f, 0.f, 0.f};

    // prefetch + convert first tile (32 floats per array -> 16 packed u32)
    unsigned ua[16], ub[16];
#pragma unroll
    for (int i = 0; i < 8; i++) {
        float4 va = *(const float4*)(ap + i * 4);
        float4 vb = *(const float4*)(bp + i * 4);
        ua[2 * i] = pkh(va.x, va.y); ua[2 * i + 1] = pkh(va.z, va.w);
        ub[2 * i] = pkh(vb.x, vb.y); ub[2 * i + 1] = pkh(vb.z, vb.w);
    }

    const int mg = (wave >> 1) * 4;
    const int ng = (wave & 1) * 4;

    for (int kt = 0; kt < EE / 64; kt++) {
        __syncthreads();
        // ---- write staged tile (4 uint4 per array) ----
#pragma unroll
        for (int q = 0; q < 4; q++) {
            int e = ((grp_s * 2 + half) * 4 + q) * 128 + l15s * 8;
            *(uint4*)(Alds + e) = make_uint4(ua[4 * q], ua[4 * q + 1], ua[4 * q + 2], ua[4 * q + 3]);
            *(uint4*)(Blds + e) = make_uint4(ub[4 * q], ub[4 * q + 1], ub[4 * q + 2], ub[4 * q + 3]);
        }
        __syncthreads();

        if (kt < EE / 64 - 1) {
            ap += 64; bp += 64;
#pragma unroll
            for (int i = 0; i < 8; i++) {
                float4 va = *(const float4*)(ap + i * 4);
                float4 vb = *(const float4*)(bp + i * 4);
                ua[2 * i] = pkh(va.x, va.y); ua[2 * i + 1] = pkh(va.z, va.w);
                ub[2 * i] = pkh(vb.x, vb.y); ub[2 * i + 1] = pkh(vb.z, vb.w);
            }
        }

        // ---- MFMA, two kc passes (keeps fragment registers at 32) ----
#pragma unroll
        for (int kc = 0; kc < 2; kc++) {
            f16x8 Af[4], Bf[4];
#pragma unroll
            for (int mc = 0; mc < 4; mc++)
                Af[mc] = *(const f16x8*)(Alds + (((mg + mc) * 2 + kc) * 4 + quad) * 128 + l15 * 8);
#pragma unroll
            for (int nc = 0; nc < 4; nc++)
                Bf[nc] = *(const f16x8*)(Blds + (((ng + nc) * 2 + kc) * 4 + quad) * 128 + l15 * 8);
#pragma unroll
            for (int mc = 0; mc < 4; mc++)
#pragma unroll
                for (int nc = 0; nc < 4; nc++)
                    acc[mc][nc] = __builtin_amdgcn_mfma_f32_16x16x32_f16(Af[mc], Bf[nc], acc[mc][nc], 0, 0, 0);
        }
    }

    // ---- epilogue: bias + RoPE + f16 RNE pack + swizzled scatter ----
    const int n0w = n0b + (wave & 1) * 64;
    const int m0w = m0 + (wave >> 1) * 64;
    const int sec = n0w >> 10;
    const int h   = (n0w & 1023) >> 6;
    const int bq  = m0w >> 11;
    const size_t abase = (size_t)(bq * NHH + h) * 131072;
    unsigned short* dst = (sec == 0) ? Qg : (sec == 1) ? Kg : Vg;

    float bn[4];
#pragma unroll
    for (int nc = 0; nc < 4; nc++) bn[nc] = bias[n0w + nc * 16 + l15];

    if (sec < 2) {
        // Q gets 0.125 * log2(e) so attention softmax can use exp2 directly
        const float scq = (sec == 0) ? 0.18033688f : 1.0f;
#pragma unroll
        for (int mc = 0; mc < 4; mc++) {
            int sb = (m0w & 2047) + mc * 16;
#pragma unroll
            for (int nc = 0; nc < 4; nc++) {
                int d = nc * 16 + l15;
                int p = d >> 1;
                int kc_d = d >> 5, quad_a = (d >> 3) & 3, j = d & 7;
#pragma unroll
                for (int rr = 0; rr < 4; rr++) {
                    int srow = sb + quad * 4 + rr;
                    float x = acc[mc][nc][rr] + bn[nc];
                    float xp = __shfl_xor(x, 1);
                    float c = ct[srow * 32 + p], sn = st[srow * 32 + p];
                    float o = ((l15 & 1) == 0) ? (x * c - xp * sn) : (xp * sn + x * c);
                    o *= scq;
                    float op = __shfl_xor(o, 1);
                    if ((l15 & 1) == 0) {
                        unsigned u = pkh(o, op);   // (d, d+1) halves
                        size_t e = abase +
                            (size_t)((((srow >> 4) * 2 + kc_d) * 4 + quad_a)) * 128 +
                            (srow & 15) * 8 + j;
                        *(unsigned int*)(dst + e) = u;
                    }
                }
            }
        }
    } else {
#pragma unroll
        for (int mc = 0; mc < 4; mc++) {
            int sb = (m0w & 2047) + mc * 16;
            int s32 = sb >> 5;
            int quad_v = ((sb >> 3) + (quad >> 1)) & 3;
            int j0 = (quad & 1) * 4;
#pragma unroll
            for (int nc = 0; nc < 4; nc++) {
                float x0 = acc[mc][nc][0] + bn[nc];
                float x1 = acc[mc][nc][1] + bn[nc];
                float x2 = acc[mc][nc][2] + bn[nc];
                float x3 = acc[mc][nc][3] + bn[nc];
                unsigned u01 = pkh(x0, x1), u23 = pkh(x2, x3);
                size_t e = abase +
                    (size_t)(((s32 * 4 + nc) * 4 + quad_v)) * 128 + l15 * 8 + j0;
                *(uint2*)(dst + e) = make_uint2(u01, u23);
            }
        }
    }
}

// ---------------- kernel 3: flash attention, f16 MFMA ---------------------
// 128-thread blocks (2 waves), 1024 blocks = 4 independent barrier groups/CU.
// K staged via DMA; V fragments direct from global (swizzled layout).
// XCD-pinned: all 32 blocks of one bh land on one XCD.
__global__ __launch_bounds__(128, 2) void attn_mfma_k(
    const unsigned short* __restrict__ Qg,
    const unsigned short* __restrict__ Kg,
    const unsigned short* __restrict__ Vg,
    float* __restrict__ out)
{
    __shared__ __align__(16) unsigned short Klds[4096];   // 64 keys x 64 d, f16: 8 KB
    __shared__ __align__(16) unsigned short Pbuf[2][1088];

    const int tid  = threadIdx.x;
    const int wave = tid >> 6;
    const int lane = tid & 63;
    const int quad = lane >> 4;
    const int l15  = lane & 15;
    const int id   = blockIdx.x;
    const int bh   = (id & 7) * 4 + ((id >> 3) & 3);   // XCD-pinned bh
    const int qt   = id >> 5;
    const int b    = bh >> 4, h = bh & 15;
    const int q_wave = qt * 64 + wave * 32;
    const size_t abase = (size_t)bh * 131072;

    // Q B-fragments (persistent)
    f16x8 qf[2][2];
#pragma unroll
    for (int nc = 0; nc < 2; nc++)
#pragma unroll
        for (int kc = 0; kc < 2; kc++)
            qf[nc][kc] = *(const f16x8*)(Qg + abase +
                (size_t)(((((q_wave >> 4) + nc) * 2 + kc) * 4 + quad)) * 128 + l15 * 8);

    f32x4 acc[2][4];
#pragma unroll
    for (int nc = 0; nc < 2; nc++)
#pragma unroll
        for (int dc = 0; dc < 4; dc++) acc[nc][dc] = (f32x4){0.f, 0.f, 0.f, 0.f};
    float mst[2] = {-INFINITY, -INFINITY};
    float lst[2] = {0.f, 0.f};

    const unsigned short* kgb = Kg + abase;
    const unsigned short* vgb = Vg + abase;

    for (int kt = 0; kt < SS / 64; kt++) {
        __syncthreads();   // previous tile's Klds reads done
#pragma unroll
        for (int i = 0; i < 4; i++)
            dma16(kgb + (size_t)kt * 4096 + (tid + i * 128) * 8,
                  Klds + (tid + i * 128) * 8);
        __syncthreads();   // drains vmcnt(0) -> K tile visible

        // ---- V fragments straight from global (consumed after softmax) ----
        const unsigned short* vt = vgb + (size_t)kt * 4096;
        f16x8 vf[4][2];
#pragma unroll
        for (int dc = 0; dc < 4; dc++)
#pragma unroll
            for (int kk2 = 0; kk2 < 2; kk2++)
                vf[dc][kk2] = *(const f16x8*)(vt + (kk2 * 16 + dc * 4 + quad) * 128 + l15 * 8);

        // ---- QK^T (transposed: St[key][q]), scores in log2 domain ----
        f32x4 stt[2][4];
#pragma unroll
        for (int mc = 0; mc < 4; mc++) {
            f16x8 a0 = *(const f16x8*)(Klds + ((mc * 2 + 0) * 4 + quad) * 128 + l15 * 8);
            f16x8 a1 = *(const f16x8*)(Klds + ((mc * 2 + 1) * 4 + quad) * 128 + l15 * 8);
#pragma unroll
            for (int nc = 0; nc < 2; nc++) {
                f32x4 s = (f32x4){0.f, 0.f, 0.f, 0.f};
                s = __builtin_amdgcn_mfma_f32_16x16x32_f16(a0, qf[nc][0], s, 0, 0, 0);
                s = __builtin_amdgcn_mfma_f32_16x16x32_f16(a1, qf[nc][1], s, 0, 0, 0);
                stt[nc][mc] = s;
            }
        }

#pragma unroll
        for (int nc = 0; nc < 2; nc++) {
            float mt = -INFINITY;
#pragma unroll
            for (int mc = 0; mc < 4; mc++)
#pragma unroll
                for (int rr = 0; rr < 4; rr++) mt = fmaxf(mt, stt[nc][mc][rr]);
            mt = fmaxf(mt, __shfl_xor(mt, 16));
            mt = fmaxf(mt, __shfl_xor(mt, 32));
            float mnew = fmaxf(mst[nc], mt);
            float alpha = __builtin_amdgcn_exp2f(mst[nc] - mnew);
            float p[4][4];
            float ps = 0.f;
#pragma unroll
            for (int mc = 0; mc < 4; mc++)
#pragma unroll
                for (int rr = 0; rr < 4; rr++) {
                    float e = __builtin_amdgcn_exp2f(stt[nc][mc][rr] - mnew);
                    p[mc][rr] = e;
                    ps += e;
                }
            ps += __shfl_xor(ps, 16);
            ps += __shfl_xor(ps, 32);
            lst[nc] = lst[nc] * alpha + ps;
            mst[nc] = mnew;

            float ar[4];
#pragma unroll
            for (int rr = 0; rr < 4; rr++)
                ar[rr] = __shfl(alpha, (lane & 48) + ((lane >> 4) << 2) + rr);
#pragma unroll
            for (int dc = 0; dc < 4; dc++)
#pragma unroll
                for (int rr = 0; rr < 4; rr++) acc[nc][dc][rr] *= ar[rr];

            // pack P (f16 RNE), LDS round-trip into A-operand layout
            unsigned short* Pw = Pbuf[wave];
#pragma unroll
            for (int mc = 0; mc < 4; mc++)
#pragma unroll
                for (int pr = 0; pr < 2; pr++) {
                    unsigned u = pkh(p[mc][2 * pr], p[mc][2 * pr + 1]);
                    int kk2 = mc >> 1;
                    int quadp = (mc & 1) * 2 + (quad >> 1);
                    int j = (quad & 1) * 4 + 2 * pr;
                    *(unsigned int*)(Pw + (kk2 * 4 + quadp) * 136 + l15 * 8 + j) = u;
                }
            f16x8 pf[2];
#pragma unroll
            for (int kk2 = 0; kk2 < 2; kk2++)
                pf[kk2] = *(const f16x8*)(Pw + (kk2 * 4 + quad) * 136 + l15 * 8);

            // ---- PV ----
#pragma unroll
            for (int dc = 0; dc < 4; dc++) {
                f32x4 aa = acc[nc][dc];
#pragma unroll
                for (int kk2 = 0; kk2 < 2; kk2++)
                    aa = __builtin_amdgcn_mfma_f32_16x16x32_f16(pf[kk2], vf[dc][kk2], aa, 0, 0, 0);
                acc[nc][dc] = aa;
            }
        }
    }

#pragma unroll
    for (int nc = 0; nc < 2; nc++) {
        float linv = 1.f / lst[nc];
        float lr[4];
#pragma unroll
        for (int rr = 0; rr < 4; rr++)
            lr[rr] = __shfl(linv, (lane & 48) + ((lane >> 4) << 2) + rr);
#pragma unroll
        for (int dc = 0; dc < 4; dc++)
#pragma unroll
            for (int rr = 0; rr < 4; rr++) {
                int s = q_wave + nc * 16 + quad * 4 + rr;
                out[((size_t)(b * SS + s)) * EE + h * HD + dc * 16 + l15] = acc[nc][dc][rr] * lr[rr];
            }
    }
}

extern "C" void kernel_launch(void* const* d_in, const int* in_sizes, int n_in,
                              void* d_out, int out_size, void* d_ws, size_t ws_size,
                              hipStream_t stream) {
    const float* X    = (const float*)d_in[0];
    const float* W    = (const float*)d_in[1];
    const float* bias = (const float*)d_in[2];
    float* out = (float*)d_out;

    float* ws = (float*)d_ws;
    float* ct = ws;                    // 65536 f32
    float* st = ws + 65536;            // 65536 f32
    unsigned short* base = (unsigned short*)(ws + 131072);
    const size_t ASZ = (size_t)32 * 131072;   // 4.19M f16 per array
    unsigned short* Qg = base;
    unsigned short* Kg = base + ASZ;
    unsigned short* Vg = base + 2 * ASZ;

    rope_table_k<<<(SS * HD2 + 255) / 256, 256, 0, stream>>>(ct, st);
    qkv_mfma_k<<<dim3(3 * EE / 128, BB * SS / 128), 256, 0, stream>>>(
        X, W, bias, ct, st, Qg, Kg, Vg);
    attn_mfma_k<<<dim3(1024), 128, 0, stream>>>(Qg, Kg, Vg, out);
}

// Round 9
// 215.894 us; speedup vs baseline: 1.4408x; 1.4408x over previous
//
#include <hip/hip_runtime.h>
#include <math.h>

// Problem constants: B=2, S=2048, E=1024, NH=16, hd=64, T=1 (seq = S)
#define BB 2
#define SS 2048
#define EE 1024
#define NHH 16
#define HD 64
#define HD2 32

typedef _Float16 f16x8 __attribute__((ext_vector_type(8)));   // 8 f16 = 4 VGPRs
typedef __attribute__((ext_vector_type(4))) float f32x4;      // MFMA accumulator

// pack two fp32 -> half2 with RNE (v_cvt_f16_f32 x2 + pack). RNE is essential:
// RTZ's one-sided bias accumulates over K=1024 dots.
static __device__ __forceinline__ unsigned pkh(float a, float b) {
    union { _Float16 h[2]; unsigned u; } v;
    v.h[0] = (_Float16)a; v.h[1] = (_Float16)b;
    return v.u;
}

// ---- async global->LDS DMA, 16B per lane (global_load_lds_dwordx4) ----
static __device__ __forceinline__ void dma16(const void* g, void* l) {
    __builtin_amdgcn_global_load_lds(
        (const __attribute__((address_space(1))) unsigned int*)g,
        (__attribute__((address_space(3))) unsigned int*)l,
        16, 0, 0);
}

// ---------------- kernel 1: RoPE cos/sin tables ----------------
__global__ __launch_bounds__(256) void rope_table_k(float* __restrict__ ct,
                                                    float* __restrict__ st) {
    int idx = blockIdx.x * 256 + threadIdx.x;   // idx = s*32 + p
    if (idx >= SS * HD2) return;
    int s = idx >> 5, p = idx & 31;
    double inv = pow(10000.0, -(double)(2 * p) / 64.0);
    double ang = (double)s * inv;
    ct[idx] = (float)cos(ang);
    st[idx] = (float)sin(ang);
}

// ---------------- kernel 2: QKV GEMM (f16 RNE, single-product MFMA) -------
// C = X @ W^T + bias. 128x128 tile, BK=32 (32 iters), 4 waves each 64x64.
// CRITICAL (r8 post-mortem): prefetch raw float4; CONVERT ONLY AFTER the next
// barrier, so the loads' first consumer sits past the MFMA section and the
// compiler's vmcnt wait lands where latency is already hidden.
__global__ __launch_bounds__(256, 3) void qkv_mfma_k(
    const float* __restrict__ X, const float* __restrict__ W,
    const float* __restrict__ bias,
    const float* __restrict__ ct, const float* __restrict__ st,
    unsigned short* __restrict__ Qg, unsigned short* __restrict__ Kg,
    unsigned short* __restrict__ Vg)
{
    __shared__ __align__(16) unsigned short Alds[4096];   // 128 rows x 32 k, f16: 8 KB
    __shared__ __align__(16) unsigned short Blds[4096];

    const int tid  = threadIdx.x;
    const int wave = tid >> 6;
    const int lane = tid & 63;
    const int quad = lane >> 4;
    const int l15  = lane & 15;
    const int m0   = blockIdx.y * 128;
    const int n0b  = blockIdx.x * 128;

    // staging: row r (0..127), k-segment ks (0 or 16) -> quads q0s, q0s+1
    const int r  = tid >> 1;
    const int ks = (tid & 1) * 16;
    const int q0s = ks >> 3;
    const int grp_s = r >> 4;
    const int l15s  = r & 15;

    const float* ap = X + (size_t)(m0 + r) * EE + ks;
    const float* bp = W + (size_t)(n0b + r) * EE + ks;

    f32x4 acc[4][4];
#pragma unroll
    for (int mc = 0; mc < 4; mc++)
#pragma unroll
        for (int nc = 0; nc < 4; nc++) acc[mc][nc] = (f32x4){0.f, 0.f, 0.f, 0.f};

    // prefetch first tile RAW (no conversion here!)
    float4 a[4], bb[4];
#pragma unroll
    for (int i = 0; i < 4; i++) {
        a[i]  = *(const float4*)(ap + i * 4);
        bb[i] = *(const float4*)(bp + i * 4);
    }

    const int mg = (wave >> 1) * 4;
    const int ng = (wave & 1) * 4;

    for (int kt = 0; kt < EE / 32; kt++) {
        __syncthreads();
        // ---- convert (f16 RNE) + write staged tile ----
#pragma unroll
        for (int half = 0; half < 2; half++) {
            int q = q0s + half;
            const float* fa = (const float*)&a[half * 2];
            const float* fb = (const float*)&bb[half * 2];
            unsigned uaw[4], ubw[4];
#pragma unroll
            for (int jj = 0; jj < 4; jj++) {
                uaw[jj] = pkh(fa[2 * jj], fa[2 * jj + 1]);
                ubw[jj] = pkh(fb[2 * jj], fb[2 * jj + 1]);
            }
            int e = (grp_s * 4 + q) * 128 + l15s * 8;
            *(uint4*)(Alds + e) = make_uint4(uaw[0], uaw[1], uaw[2], uaw[3]);
            *(uint4*)(Blds + e) = make_uint4(ubw[0], ubw[1], ubw[2], ubw[3]);
        }
        __syncthreads();

        // ---- prefetch next tile raw (consumed only after NEXT barrier) ----
        if (kt < EE / 32 - 1) {
            ap += 32; bp += 32;
#pragma unroll
            for (int i = 0; i < 4; i++) {
                a[i]  = *(const float4*)(ap + i * 4);
                bb[i] = *(const float4*)(bp + i * 4);
            }
        }

        // ---- fragments + MFMA (16 per iter) ----
        f16x8 Af[4], Bf[4];
#pragma unroll
        for (int mc = 0; mc < 4; mc++)
            Af[mc] = *(const f16x8*)(Alds + ((mg + mc) * 4 + quad) * 128 + l15 * 8);
#pragma unroll
        for (int nc = 0; nc < 4; nc++)
            Bf[nc] = *(const f16x8*)(Blds + ((ng + nc) * 4 + quad) * 128 + l15 * 8);
#pragma unroll
        for (int mc = 0; mc < 4; mc++)
#pragma unroll
            for (int nc = 0; nc < 4; nc++)
                acc[mc][nc] = __builtin_amdgcn_mfma_f32_16x16x32_f16(Af[mc], Bf[nc], acc[mc][nc], 0, 0, 0);
    }

    // ---- epilogue: bias + RoPE + f16 RNE pack + swizzled scatter ----
    const int n0w = n0b + (wave & 1) * 64;
    const int m0w = m0 + (wave >> 1) * 64;
    const int sec = n0w >> 10;
    const int h   = (n0w & 1023) >> 6;
    const int bq  = m0w >> 11;
    const size_t abase = (size_t)(bq * NHH + h) * 131072;
    unsigned short* dst = (sec == 0) ? Qg : (sec == 1) ? Kg : Vg;

    float bn[4];
#pragma unroll
    for (int nc = 0; nc < 4; nc++) bn[nc] = bias[n0w + nc * 16 + l15];

    if (sec < 2) {
        // Q gets 0.125 * log2(e) so attention softmax can use exp2 directly
        const float scq = (sec == 0) ? 0.18033688f : 1.0f;
#pragma unroll
        for (int mc = 0; mc < 4; mc++) {
            int sb = (m0w & 2047) + mc * 16;
#pragma unroll
            for (int nc = 0; nc < 4; nc++) {
                int d = nc * 16 + l15;
                int p = d >> 1;
                int kc_d = d >> 5, quad_a = (d >> 3) & 3, j = d & 7;
#pragma unroll
                for (int rr = 0; rr < 4; rr++) {
                    int srow = sb + quad * 4 + rr;
                    float x = acc[mc][nc][rr] + bn[nc];
                    float xp = __shfl_xor(x, 1);
                    float c = ct[srow * 32 + p], sn = st[srow * 32 + p];
                    float o = ((l15 & 1) == 0) ? (x * c - xp * sn) : (xp * sn + x * c);
                    o *= scq;
                    float op = __shfl_xor(o, 1);
                    if ((l15 & 1) == 0) {
                        unsigned u = pkh(o, op);   // (d, d+1) halves
                        size_t e = abase +
                            (size_t)((((srow >> 4) * 2 + kc_d) * 4 + quad_a)) * 128 +
                            (srow & 15) * 8 + j;
                        *(unsigned int*)(dst + e) = u;
                    }
                }
            }
        }
    } else {
#pragma unroll
        for (int mc = 0; mc < 4; mc++) {
            int sb = (m0w & 2047) + mc * 16;
            int s32 = sb >> 5;
            int quad_v = ((sb >> 3) + (quad >> 1)) & 3;
            int j0 = (quad & 1) * 4;
#pragma unroll
            for (int nc = 0; nc < 4; nc++) {
                float x0 = acc[mc][nc][0] + bn[nc];
                float x1 = acc[mc][nc][1] + bn[nc];
                float x2 = acc[mc][nc][2] + bn[nc];
                float x3 = acc[mc][nc][3] + bn[nc];
                unsigned u01 = pkh(x0, x1), u23 = pkh(x2, x3);
                size_t e = abase +
                    (size_t)(((s32 * 4 + nc) * 4 + quad_v)) * 128 + l15 * 8 + j0;
                *(uint2*)(dst + e) = make_uint2(u01, u23);
            }
        }
    }
}

// ---------------- kernel 3: flash attention, f16 MFMA ---------------------
// (unchanged from round 8 so its counters become visible this round)
__global__ __launch_bounds__(128, 2) void attn_mfma_k(
    const unsigned short* __restrict__ Qg,
    const unsigned short* __restrict__ Kg,
    const unsigned short* __restrict__ Vg,
    float* __restrict__ out)
{
    __shared__ __align__(16) unsigned short Klds[4096];   // 64 keys x 64 d, f16: 8 KB
    __shared__ __align__(16) unsigned short Pbuf[2][1088];

    const int tid  = threadIdx.x;
    const int wave = tid >> 6;
    const int lane = tid & 63;
    const int quad = lane >> 4;
    const int l15  = lane & 15;
    const int id   = blockIdx.x;
    const int bh   = (id & 7) * 4 + ((id >> 3) & 3);   // XCD-pinned bh
    const int qt   = id >> 5;
    const int b    = bh >> 4, h = bh & 15;
    const int q_wave = qt * 64 + wave * 32;
    const size_t abase = (size_t)bh * 131072;

    f16x8 qf[2][2];
#pragma unroll
    for (int nc = 0; nc < 2; nc++)
#pragma unroll
        for (int kc = 0; kc < 2; kc++)
            qf[nc][kc] = *(const f16x8*)(Qg + abase +
                (size_t)(((((q_wave >> 4) + nc) * 2 + kc) * 4 + quad)) * 128 + l15 * 8);

    f32x4 acc[2][4];
#pragma unroll
    for (int nc = 0; nc < 2; nc++)
#pragma unroll
        for (int dc = 0; dc < 4; dc++) acc[nc][dc] = (f32x4){0.f, 0.f, 0.f, 0.f};
    float mst[2] = {-INFINITY, -INFINITY};
    float lst[2] = {0.f, 0.f};

    const unsigned short* kgb = Kg + abase;
    const unsigned short* vgb = Vg + abase;

    for (int kt = 0; kt < SS / 64; kt++) {
        __syncthreads();   // previous tile's Klds reads done
#pragma unroll
        for (int i = 0; i < 4; i++)
            dma16(kgb + (size_t)kt * 4096 + (tid + i * 128) * 8,
                  Klds + (tid + i * 128) * 8);
        __syncthreads();   // drains vmcnt(0) -> K tile visible

        const unsigned short* vt = vgb + (size_t)kt * 4096;
        f16x8 vf[4][2];
#pragma unroll
        for (int dc = 0; dc < 4; dc++)
#pragma unroll
            for (int kk2 = 0; kk2 < 2; kk2++)
                vf[dc][kk2] = *(const f16x8*)(vt + (kk2 * 16 + dc * 4 + quad) * 128 + l15 * 8);

        f32x4 stt[2][4];
#pragma unroll
        for (int mc = 0; mc < 4; mc++) {
            f16x8 a0 = *(const f16x8*)(Klds + ((mc * 2 + 0) * 4 + quad) * 128 + l15 * 8);
            f16x8 a1 = *(const f16x8*)(Klds + ((mc * 2 + 1) * 4 + quad) * 128 + l15 * 8);
#pragma unroll
            for (int nc = 0; nc < 2; nc++) {
                f32x4 s = (f32x4){0.f, 0.f, 0.f, 0.f};
                s = __builtin_amdgcn_mfma_f32_16x16x32_f16(a0, qf[nc][0], s, 0, 0, 0);
                s = __builtin_amdgcn_mfma_f32_16x16x32_f16(a1, qf[nc][1], s, 0, 0, 0);
                stt[nc][mc] = s;
            }
        }

#pragma unroll
        for (int nc = 0; nc < 2; nc++) {
            float mt = -INFINITY;
#pragma unroll
            for (int mc = 0; mc < 4; mc++)
#pragma unroll
                for (int rr = 0; rr < 4; rr++) mt = fmaxf(mt, stt[nc][mc][rr]);
            mt = fmaxf(mt, __shfl_xor(mt, 16));
            mt = fmaxf(mt, __shfl_xor(mt, 32));
            float mnew = fmaxf(mst[nc], mt);
            float alpha = __builtin_amdgcn_exp2f(mst[nc] - mnew);
            float p[4][4];
            float ps = 0.f;
#pragma unroll
            for (int mc = 0; mc < 4; mc++)
#pragma unroll
                for (int rr = 0; rr < 4; rr++) {
                    float e = __builtin_amdgcn_exp2f(stt[nc][mc][rr] - mnew);
                    p[mc][rr] = e;
                    ps += e;
                }
            ps += __shfl_xor(ps, 16);
            ps += __shfl_xor(ps, 32);
            lst[nc] = lst[nc] * alpha + ps;
            mst[nc] = mnew;

            float ar[4];
#pragma unroll
            for (int rr = 0; rr < 4; rr++)
                ar[rr] = __shfl(alpha, (lane & 48) + ((lane >> 4) << 2) + rr);
#pragma unroll
            for (int dc = 0; dc < 4; dc++)
#pragma unroll
                for (int rr = 0; rr < 4; rr++) acc[nc][dc][rr] *= ar[rr];

            unsigned short* Pw = Pbuf[wave];
#pragma unroll
            for (int mc = 0; mc < 4; mc++)
#pragma unroll
                for (int pr = 0; pr < 2; pr++) {
                    unsigned u = pkh(p[mc][2 * pr], p[mc][2 * pr + 1]);
                    int kk2 = mc >> 1;
                    int quadp = (mc & 1) * 2 + (quad >> 1);
                    int j = (quad & 1) * 4 + 2 * pr;
                    *(unsigned int*)(Pw + (kk2 * 4 + quadp) * 136 + l15 * 8 + j) = u;
                }
            f16x8 pf[2];
#pragma unroll
            for (int kk2 = 0; kk2 < 2; kk2++)
                pf[kk2] = *(const f16x8*)(Pw + (kk2 * 4 + quad) * 136 + l15 * 8);

#pragma unroll
            for (int dc = 0; dc < 4; dc++) {
                f32x4 aa = acc[nc][dc];
#pragma unroll
                for (int kk2 = 0; kk2 < 2; kk2++)
                    aa = __builtin_amdgcn_mfma_f32_16x16x32_f16(pf[kk2], vf[dc][kk2], aa, 0, 0, 0);
                acc[nc][dc] = aa;
            }
        }
    }

#pragma unroll
    for (int nc = 0; nc < 2; nc++) {
        float linv = 1.f / lst[nc];
        float lr[4];
#pragma unroll
        for (int rr = 0; rr < 4; rr++)
            lr[rr] = __shfl(linv, (lane & 48) + ((lane >> 4) << 2) + rr);
#pragma unroll
        for (int dc = 0; dc < 4; dc++)
#pragma unroll
            for (int rr = 0; rr < 4; rr++) {
                int s = q_wave + nc * 16 + quad * 4 + rr;
                out[((size_t)(b * SS + s)) * EE + h * HD + dc * 16 + l15] = acc[nc][dc][rr] * lr[rr];
            }
    }
}

extern "C" void kernel_launch(void* const* d_in, const int* in_sizes, int n_in,
                              void* d_out, int out_size, void* d_ws, size_t ws_size,
                              hipStream_t stream) {
    const float* X    = (const float*)d_in[0];
    const float* W    = (const float*)d_in[1];
    const float* bias = (const float*)d_in[2];
    float* out = (float*)d_out;

    float* ws = (float*)d_ws;
    float* ct = ws;                    // 65536 f32
    float* st = ws + 65536;            // 65536 f32
    unsigned short* base = (unsigned short*)(ws + 131072);
    const size_t ASZ = (size_t)32 * 131072;   // 4.19M f16 per array
    unsigned short* Qg = base;
    unsigned short* Kg = base + ASZ;
    unsigned short* Vg = base + 2 * ASZ;

    rope_table_k<<<(SS * HD2 + 255) / 256, 256, 0, stream>>>(ct, st);
    qkv_mfma_k<<<dim3(3 * EE / 128, BB * SS / 128), 256, 0, stream>>>(
        X, W, bias, ct, st, Qg, Kg, Vg);
    attn_mfma_k<<<dim3(1024), 128, 0, stream>>>(Qg, Kg, Vg, out);
}

// Round 10
// 188.611 us; speedup vs baseline: 1.6492x; 1.1447x over previous
//
#include <hip/hip_runtime.h>
#include <math.h>

// Problem constants: B=2, S=2048, E=1024, NH=16, hd=64, T=1 (seq = S)
#define BB 2
#define SS 2048
#define EE 1024
#define NHH 16
#define HD 64
#define HD2 32

typedef _Float16 f16x8 __attribute__((ext_vector_type(8)));   // 8 f16 = 4 VGPRs
typedef __attribute__((ext_vector_type(4))) float f32x4;      // MFMA accumulator

// pack two fp32 -> half2 with RNE (v_cvt_f16_f32 x2 + pack)
static __device__ __forceinline__ unsigned pkh(float a, float b) {
    union { _Float16 h[2]; unsigned u; } v;
    v.h[0] = (_Float16)a; v.h[1] = (_Float16)b;
    return v.u;
}

// ---- async global->LDS DMA, 16B per lane (global_load_lds_dwordx4) ----
static __device__ __forceinline__ void dma16(const void* g, void* l) {
    __builtin_amdgcn_global_load_lds(
        (const __attribute__((address_space(1))) unsigned int*)g,
        (__attribute__((address_space(3))) unsigned int*)l,
        16, 0, 0);
}

// ---------------- kernel 1: RoPE cos/sin tables ----------------
__global__ __launch_bounds__(256) void rope_table_k(float* __restrict__ ct,
                                                    float* __restrict__ st) {
    int idx = blockIdx.x * 256 + threadIdx.x;   // idx = s*32 + p
    if (idx >= SS * HD2) return;
    int s = idx >> 5, p = idx & 31;
    double inv = pow(10000.0, -(double)(2 * p) / 64.0);
    double ang = (double)s * inv;
    ct[idx] = (float)cos(ang);
    st[idx] = (float)sin(ang);
}

// ---------------- kernel 1b: fp32 -> f16 pre-convert, LDS-tile order ------
// Dest linear chunk index (16B = 8 f16): ((((t*32+kt)*8+grp)*4+q)*16+l15)
// where t = row-tile (X: mt 0..31, W: nt 0..23), row = t*128+grp*16+l15,
// k = kt*32+q*8. This equals the GEMM's LDS layout, so staging is a straight
// dma16 copy. One thread per chunk; reads 32B/thread, 128B-contig per row.
#define NXCHUNK 524288    // 4096*1024/8
#define NWCHUNK 393216    // 3072*1024/8
__global__ __launch_bounds__(256) void cvt_k(
    const float* __restrict__ X, const float* __restrict__ W,
    unsigned short* __restrict__ Xh, unsigned short* __restrict__ Wh)
{
    int idx = blockIdx.x * 256 + threadIdx.x;
    const float* src;
    unsigned short* dst;
    int c;
    if (idx < NXCHUNK) { src = X; dst = Xh; c = idx; }
    else               { src = W; dst = Wh; c = idx - NXCHUNK;
                         if (c >= NWCHUNK) return; }
    int l15 = c & 15, q = (c >> 4) & 3, grp = (c >> 6) & 7;
    int kt = (c >> 9) & 31, t = c >> 14;
    int row = t * 128 + grp * 16 + l15;
    int k   = kt * 32 + q * 8;
    float4 v0 = *(const float4*)(src + (size_t)row * EE + k);
    float4 v1 = *(const float4*)(src + (size_t)row * EE + k + 4);
    *(uint4*)(dst + (size_t)c * 8) =
        make_uint4(pkh(v0.x, v0.y), pkh(v0.z, v0.w), pkh(v1.x, v1.y), pkh(v1.z, v1.w));
}

// ---------------- kernel 2: QKV GEMM (f16, dma16-staged, m97 structure) ---
// C = X @ W^T + bias. 128x128 tile, BK=32 (32 iters), 4 waves each 64x64.
// K-loop: dma16 -> barrier -> ds_read_b128 -> 16 MFMA. No conversion VALU,
// no prefetch registers. XCD-pinned grid: each XCD owns 3 n-tiles so its W
// working set (768 KB f16) stays in its 4 MB L2.
__global__ __launch_bounds__(256, 3) void qkv_mfma_k(
    const unsigned short* __restrict__ Xh, const unsigned short* __restrict__ Wh,
    const float* __restrict__ bias,
    const float* __restrict__ ct, const float* __restrict__ st,
    unsigned short* __restrict__ Qg, unsigned short* __restrict__ Kg,
    unsigned short* __restrict__ Vg)
{
    __shared__ __align__(16) unsigned short Alds[4096];   // 128 x 32 f16: 8 KB
    __shared__ __align__(16) unsigned short Blds[4096];

    const int tid  = threadIdx.x;
    const int wave = tid >> 6;
    const int lane = tid & 63;
    const int quad = lane >> 4;
    const int l15  = lane & 15;

    // XCD-pinned decode: 768 blocks, id&7 = XCD, 96 blocks/XCD = 3 nt x 32 mt
    const int id    = blockIdx.x;
    const int xcd   = id & 7;
    const int local = id >> 3;
    const int nt    = xcd * 3 + local % 3;
    const int mt    = local / 3;
    const int m0    = mt * 128;
    const int n0b   = nt * 128;

    f32x4 acc[4][4];
#pragma unroll
    for (int mc = 0; mc < 4; mc++)
#pragma unroll
        for (int nc = 0; nc < 4; nc++) acc[mc][nc] = (f32x4){0.f, 0.f, 0.f, 0.f};

    const int mg = (wave >> 1) * 4;
    const int ng = (wave & 1) * 4;

    for (int kt = 0; kt < EE / 32; kt++) {
        __syncthreads();   // previous iteration's fragment reads done
        {
            const unsigned short* at = Xh + ((size_t)(mt * 32 + kt)) * 4096;
            const unsigned short* bt = Wh + ((size_t)(nt * 32 + kt)) * 4096;
            dma16(at + (size_t)tid * 8,         Alds + tid * 8);
            dma16(at + (size_t)(tid + 256) * 8, Alds + (tid + 256) * 8);
            dma16(bt + (size_t)tid * 8,         Blds + tid * 8);
            dma16(bt + (size_t)(tid + 256) * 8, Blds + (tid + 256) * 8);
        }
        __syncthreads();   // drains vmcnt(0) -> tiles visible

        f16x8 Af[4], Bf[4];
#pragma unroll
        for (int mc = 0; mc < 4; mc++)
            Af[mc] = *(const f16x8*)(Alds + ((mg + mc) * 4 + quad) * 128 + l15 * 8);
#pragma unroll
        for (int nc = 0; nc < 4; nc++)
            Bf[nc] = *(const f16x8*)(Blds + ((ng + nc) * 4 + quad) * 128 + l15 * 8);
#pragma unroll
        for (int mc = 0; mc < 4; mc++)
#pragma unroll
            for (int nc = 0; nc < 4; nc++)
                acc[mc][nc] = __builtin_amdgcn_mfma_f32_16x16x32_f16(Af[mc], Bf[nc], acc[mc][nc], 0, 0, 0);
    }

    // ---- epilogue: bias + RoPE + f16 RNE pack + swizzled scatter ----
    const int n0w = n0b + (wave & 1) * 64;
    const int m0w = m0 + (wave >> 1) * 64;
    const int sec = n0w >> 10;
    const int h   = (n0w & 1023) >> 6;
    const int bq  = m0w >> 11;
    const size_t abase = (size_t)(bq * NHH + h) * 131072;
    unsigned short* dst = (sec == 0) ? Qg : (sec == 1) ? Kg : Vg;

    float bn[4];
#pragma unroll
    for (int nc = 0; nc < 4; nc++) bn[nc] = bias[n0w + nc * 16 + l15];

    if (sec < 2) {
        // Q gets 0.125 * log2(e) so attention softmax can use exp2 directly
        const float scq = (sec == 0) ? 0.18033688f : 1.0f;
#pragma unroll
        for (int mc = 0; mc < 4; mc++) {
            int sb = (m0w & 2047) + mc * 16;
#pragma unroll
            for (int nc = 0; nc < 4; nc++) {
                int d = nc * 16 + l15;
                int p = d >> 1;
                int kc_d = d >> 5, quad_a = (d >> 3) & 3, j = d & 7;
#pragma unroll
                for (int rr = 0; rr < 4; rr++) {
                    int srow = sb + quad * 4 + rr;
                    float x = acc[mc][nc][rr] + bn[nc];
                    float xp = __shfl_xor(x, 1);
                    float c = ct[srow * 32 + p], sn = st[srow * 32 + p];
                    float o = ((l15 & 1) == 0) ? (x * c - xp * sn) : (xp * sn + x * c);
                    o *= scq;
                    float op = __shfl_xor(o, 1);
                    if ((l15 & 1) == 0) {
                        unsigned u = pkh(o, op);   // (d, d+1) halves
                        size_t e = abase +
                            (size_t)((((srow >> 4) * 2 + kc_d) * 4 + quad_a)) * 128 +
                            (srow & 15) * 8 + j;
                        *(unsigned int*)(dst + e) = u;
                    }
                }
            }
        }
    } else {
#pragma unroll
        for (int mc = 0; mc < 4; mc++) {
            int sb = (m0w & 2047) + mc * 16;
            int s32 = sb >> 5;
            int quad_v = ((sb >> 3) + (quad >> 1)) & 3;
            int j0 = (quad & 1) * 4;
#pragma unroll
            for (int nc = 0; nc < 4; nc++) {
                float x0 = acc[mc][nc][0] + bn[nc];
                float x1 = acc[mc][nc][1] + bn[nc];
                float x2 = acc[mc][nc][2] + bn[nc];
                float x3 = acc[mc][nc][3] + bn[nc];
                unsigned u01 = pkh(x0, x1), u23 = pkh(x2, x3);
                size_t e = abase +
                    (size_t)(((s32 * 4 + nc) * 4 + quad_v)) * 128 + l15 * 8 + j0;
                *(uint2*)(dst + e) = make_uint2(u01, u23);
            }
        }
    }
}

// ---------------- kernel 3: flash attention, f16 MFMA (unchanged r9) ------
__global__ __launch_bounds__(128, 2) void attn_mfma_k(
    const unsigned short* __restrict__ Qg,
    const unsigned short* __restrict__ Kg,
    const unsigned short* __restrict__ Vg,
    float* __restrict__ out)
{
    __shared__ __align__(16) unsigned short Klds[4096];   // 64 keys x 64 d, f16: 8 KB
    __shared__ __align__(16) unsigned short Pbuf[2][1088];

    const int tid  = threadIdx.x;
    const int wave = tid >> 6;
    const int lane = tid & 63;
    const int quad = lane >> 4;
    const int l15  = lane & 15;
    const int id   = blockIdx.x;
    const int bh   = (id & 7) * 4 + ((id >> 3) & 3);   // XCD-pinned bh
    const int qt   = id >> 5;
    const int b    = bh >> 4, h = bh & 15;
    const int q_wave = qt * 64 + wave * 32;
    const size_t abase = (size_t)bh * 131072;

    f16x8 qf[2][2];
#pragma unroll
    for (int nc = 0; nc < 2; nc++)
#pragma unroll
        for (int kc = 0; kc < 2; kc++)
            qf[nc][kc] = *(const f16x8*)(Qg + abase +
                (size_t)(((((q_wave >> 4) + nc) * 2 + kc) * 4 + quad)) * 128 + l15 * 8);

    f32x4 acc[2][4];
#pragma unroll
    for (int nc = 0; nc < 2; nc++)
#pragma unroll
        for (int dc = 0; dc < 4; dc++) acc[nc][dc] = (f32x4){0.f, 0.f, 0.f, 0.f};
    float mst[2] = {-INFINITY, -INFINITY};
    float lst[2] = {0.f, 0.f};

    const unsigned short* kgb = Kg + abase;
    const unsigned short* vgb = Vg + abase;

    for (int kt = 0; kt < SS / 64; kt++) {
        __syncthreads();   // previous tile's Klds reads done
#pragma unroll
        for (int i = 0; i < 4; i++)
            dma16(kgb + (size_t)kt * 4096 + (tid + i * 128) * 8,
                  Klds + (tid + i * 128) * 8);
        __syncthreads();   // drains vmcnt(0) -> K tile visible

        const unsigned short* vt = vgb + (size_t)kt * 4096;
        f16x8 vf[4][2];
#pragma unroll
        for (int dc = 0; dc < 4; dc++)
#pragma unroll
            for (int kk2 = 0; kk2 < 2; kk2++)
                vf[dc][kk2] = *(const f16x8*)(vt + (kk2 * 16 + dc * 4 + quad) * 128 + l15 * 8);

        f32x4 stt[2][4];
#pragma unroll
        for (int mc = 0; mc < 4; mc++) {
            f16x8 a0 = *(const f16x8*)(Klds + ((mc * 2 + 0) * 4 + quad) * 128 + l15 * 8);
            f16x8 a1 = *(const f16x8*)(Klds + ((mc * 2 + 1) * 4 + quad) * 128 + l15 * 8);
#pragma unroll
            for (int nc = 0; nc < 2; nc++) {
                f32x4 s = (f32x4){0.f, 0.f, 0.f, 0.f};
                s = __builtin_amdgcn_mfma_f32_16x16x32_f16(a0, qf[nc][0], s, 0, 0, 0);
                s = __builtin_amdgcn_mfma_f32_16x16x32_f16(a1, qf[nc][1], s, 0, 0, 0);
                stt[nc][mc] = s;
            }
        }

#pragma unroll
        for (int nc = 0; nc < 2; nc++) {
            float mt = -INFINITY;
#pragma unroll
            for (int mc = 0; mc < 4; mc++)
#pragma unroll
                for (int rr = 0; rr < 4; rr++) mt = fmaxf(mt, stt[nc][mc][rr]);
            mt = fmaxf(mt, __shfl_xor(mt, 16));
            mt = fmaxf(mt, __shfl_xor(mt, 32));
            float mnew = fmaxf(mst[nc], mt);
            float alpha = __builtin_amdgcn_exp2f(mst[nc] - mnew);
            float p[4][4];
            float ps = 0.f;
#pragma unroll
            for (int mc = 0; mc < 4; mc++)
#pragma unroll
                for (int rr = 0; rr < 4; rr++) {
                    float e = __builtin_amdgcn_exp2f(stt[nc][mc][rr] - mnew);
                    p[mc][rr] = e;
                    ps += e;
                }
            ps += __shfl_xor(ps, 16);
            ps += __shfl_xor(ps, 32);
            lst[nc] = lst[nc] * alpha + ps;
            mst[nc] = mnew;

            float ar[4];
#pragma unroll
            for (int rr = 0; rr < 4; rr++)
                ar[rr] = __shfl(alpha, (lane & 48) + ((lane >> 4) << 2) + rr);
#pragma unroll
            for (int dc = 0; dc < 4; dc++)
#pragma unroll
                for (int rr = 0; rr < 4; rr++) acc[nc][dc][rr] *= ar[rr];

            unsigned short* Pw = Pbuf[wave];
#pragma unroll
            for (int mc = 0; mc < 4; mc++)
#pragma unroll
                for (int pr = 0; pr < 2; pr++) {
                    unsigned u = pkh(p[mc][2 * pr], p[mc][2 * pr + 1]);
                    int kk2 = mc >> 1;
                    int quadp = (mc & 1) * 2 + (quad >> 1);
                    int j = (quad & 1) * 4 + 2 * pr;
                    *(unsigned int*)(Pw + (kk2 * 4 + quadp) * 136 + l15 * 8 + j) = u;
                }
            f16x8 pf[2];
#pragma unroll
            for (int kk2 = 0; kk2 < 2; kk2++)
                pf[kk2] = *(const f16x8*)(Pw + (kk2 * 4 + quad) * 136 + l15 * 8);

#pragma unroll
            for (int dc = 0; dc < 4; dc++) {
                f32x4 aa = acc[nc][dc];
#pragma unroll
                for (int kk2 = 0; kk2 < 2; kk2++)
                    aa = __builtin_amdgcn_mfma_f32_16x16x32_f16(pf[kk2], vf[dc][kk2], aa, 0, 0, 0);
                acc[nc][dc] = aa;
            }
        }
    }

#pragma unroll
    for (int nc = 0; nc < 2; nc++) {
        float linv = 1.f / lst[nc];
        float lr[4];
#pragma unroll
        for (int rr = 0; rr < 4; rr++)
            lr[rr] = __shfl(linv, (lane & 48) + ((lane >> 4) << 2) + rr);
#pragma unroll
        for (int dc = 0; dc < 4; dc++)
#pragma unroll
            for (int rr = 0; rr < 4; rr++) {
                int s = q_wave + nc * 16 + quad * 4 + rr;
                out[((size_t)(b * SS + s)) * EE + h * HD + dc * 16 + l15] = acc[nc][dc][rr] * lr[rr];
            }
    }
}

extern "C" void kernel_launch(void* const* d_in, const int* in_sizes, int n_in,
                              void* d_out, int out_size, void* d_ws, size_t ws_size,
                              hipStream_t stream) {
    const float* X    = (const float*)d_in[0];
    const float* W    = (const float*)d_in[1];
    const float* bias = (const float*)d_in[2];
    float* out = (float*)d_out;

    float* ws = (float*)d_ws;
    float* ct = ws;                    // 65536 f32
    float* st = ws + 65536;            // 65536 f32
    unsigned short* base = (unsigned short*)(ws + 131072);
    const size_t ASZ = (size_t)32 * 131072;   // 4.19M f16 per array
    unsigned short* Qg = base;
    unsigned short* Kg = base + ASZ;
    unsigned short* Vg = base + 2 * ASZ;
    unsigned short* Xh = base + 3 * ASZ;              // 4.19M f16 (8.4 MB)
    unsigned short* Wh = Xh + (size_t)NXCHUNK * 8;    // 3.15M f16 (6.3 MB)

    rope_table_k<<<(SS * HD2 + 255) / 256, 256, 0, stream>>>(ct, st);
    cvt_k<<<(NXCHUNK + NWCHUNK) / 256, 256, 0, stream>>>(X, W, Xh, Wh);
    qkv_mfma_k<<<dim3(768), 256, 0, stream>>>(
        Xh, Wh, bias, ct, st, Qg, Kg, Vg);
    attn_mfma_k<<<dim3(1024), 128, 0, stream>>>(Qg, Kg, Vg, out);
}